// Round 2
// baseline (52.957 us; speedup 1.0000x reference)
//
#include <hip/hip_runtime.h>

#define SEQ 128
#define SD 15
#define DBA_STRIDE 32   // floats per (b,s) record in dba_params

// Hybrid grid:
//   blocks [0, nQuat)        : quaternion chains, one row per LANE (serial in t,
//                              parallel across 128 rows/block). Writes out[...,3:7].
//   blocks [nQuat, nQuat+B)  : position prefix-scan + zeros, one row per BLOCK.
//                              Writes out[...,0:3] and out[...,7:15].
// The two block families write disjoint bytes of `out`, so no ordering or
// coherence dependency exists between them (partial-line writebacks use byte
// enables). Quat blocks go first in the grid so their 127-step serial chains
// start immediately and overlap the memory-bound pos blocks.
__global__ __launch_bounds__(128) void dba_kernel(const float* __restrict__ dba,
                                                  const float* __restrict__ gt,
                                                  float* __restrict__ out,
                                                  int nQuatBlocks, int B) {
    const int tid = threadIdx.x;

    if ((int)blockIdx.x < nQuatBlocks) {
        // ---- quaternion path: one batch row per lane ----
        const int r = blockIdx.x * 128 + tid;
        if (r >= B) return;
        const float* row = dba + (size_t)r * SEQ * DBA_STRIDE;
        const float* g   = gt  + (size_t)r * SEQ * SD;
        float q0 = g[3], q1 = g[4], q2 = g[5], q3 = g[6];
        float* o = out + (size_t)r * SEQ * SD;
        o[3] = q0; o[4] = q1; o[5] = q2; o[6] = q3;

        // dq components for step t live at floats {3,4,5,6} of record t-1.
        // Two aligned float4 loads cover them (.w of the first, .xyz of the second).
        float4 a = *reinterpret_cast<const float4*>(row);
        float4 c = *reinterpret_cast<const float4*>(row + 4);
        for (int t = 1; t < SEQ; ++t) {
            const float dq0 = a.w * 0.1f, dq1 = c.x * 0.1f,
                        dq2 = c.y * 0.1f, dq3 = c.z * 0.1f;
            // Prefetch next step's record while the chain math runs.
            if (t + 1 < SEQ) {
                const float* nxt = row + (size_t)t * DBA_STRIDE;
                a = *reinterpret_cast<const float4*>(nxt);
                c = *reinterpret_cast<const float4*>(nxt + 4);
            }
            q0 += dq0; q1 += dq1; q2 += dq2; q3 += dq3;
            const float n = q0 * q0 + q1 * q1 + q2 * q2 + q3 * q3;
            const float inv = __builtin_amdgcn_rsqf(n);   // v_rsq_f32, ~1 ulp
            q0 *= inv; q1 *= inv; q2 *= inv; q3 *= inv;
            float* ot = o + (size_t)t * SD;
            ot[3] = q0; ot[4] = q1; ot[5] = q2; ot[6] = q3;
        }
        return;
    }

    // ---- position path: one batch row per block, one step per thread ----
    const int b = blockIdx.x - nQuatBlocks;
    const int s = tid;
    const int lane = s & 63;
    const int wave = s >> 6;

    const float* rec = dba + ((size_t)b * SEQ + s) * DBA_STRIDE;
    const float4 v0 = *reinterpret_cast<const float4*>(rec);
    const float d0 = v0.x * 0.1f, d1 = v0.y * 0.1f, d2 = v0.z * 0.1f;

    // Inclusive shuffle scan within each 64-lane wave.
    float ix = d0, iy = d1, iz = d2;
    #pragma unroll
    for (int off = 1; off < 64; off <<= 1) {
        const float tx = __shfl_up(ix, off, 64);
        const float ty = __shfl_up(iy, off, 64);
        const float tz = __shfl_up(iz, off, 64);
        if (lane >= off) { ix += tx; iy += ty; iz += tz; }
    }

    // Cross-wave fixup: wave 1 adds wave 0's total.
    __shared__ float w0tot[3];
    if (wave == 0 && lane == 63) { w0tot[0] = ix; w0tot[1] = iy; w0tot[2] = iz; }
    __syncthreads();
    if (wave == 1) { ix += w0tot[0]; iy += w0tot[1]; iz += w0tot[2]; }

    // Exclusive prefix = inclusive - own delta (error ~1 ulp of the sum,
    // threshold is 0.138 absmax).
    const float ex = ix - d0, ey = iy - d1, ez = iz - d2;

    const float* g = gt + (size_t)b * SEQ * SD;   // broadcast load
    const float px = g[0], py = g[1], pz = g[2];

    float* o = out + ((size_t)b * SEQ + s) * SD;
    o[0] = px + ex;
    o[1] = py + ey;
    o[2] = pz + ez;
    // o[3..6] written by the quat blocks.
    #pragma unroll
    for (int k = 7; k < SD; ++k) o[k] = 0.f;
}

extern "C" void kernel_launch(void* const* d_in, const int* in_sizes, int n_in,
                              void* d_out, int out_size, void* d_ws, size_t ws_size,
                              hipStream_t stream) {
    const float* dba = (const float*)d_in[0];      // (B, 128, 32)
    // d_in[1] = imu_measurements — unused by the reference
    const float* gt  = (const float*)d_in[2];      // (B, 128, 15)
    float* out = (float*)d_out;                    // (B, 128, 15)

    const int B = in_sizes[0] / (SEQ * DBA_STRIDE);
    const int nQuat = (B + 127) / 128;
    dba_kernel<<<nQuat + B, 128, 0, stream>>>(dba, gt, out, nQuat, B);
}

// Round 3
// 38.331 us; speedup vs baseline: 1.3816x; 1.3816x over previous
//
#include <hip/hip_runtime.h>

#define SEQ 128
#define SD 15
#define REC 32   // floats per (b,s) record in dba_params
#define UPF 16   // quat-chain prefetch/unroll depth (records held in registers)

// ---------------------------------------------------------------------------
// K1: quaternion chains, one batch row per LANE, pure-register math.
// A 16-deep register ring of upcoming records keeps ~16 loads in flight
// (~720 cyc of chain math per refill window ≈ HBM latency), so the serial
// chain never stalls on memory.  TO_WS=true writes compact [B][SEQ][4] f32
// to workspace (per-lane sequential float4 -> L2 write-combines into full
// lines); TO_WS=false scatters into out[...,3:7] (fallback if ws too small).
// ---------------------------------------------------------------------------
template <bool TO_WS>
__global__ __launch_bounds__(64) void quat_kernel(const float* __restrict__ dba,
                                                  const float* __restrict__ gt,
                                                  float* __restrict__ dst,
                                                  int B) {
    const int r = blockIdx.x * 64 + threadIdx.x;
    if (r >= B) return;

    const float* rec = dba + (size_t)r * SEQ * REC;
    const float* g   = gt  + (size_t)r * SEQ * SD;
    float q0 = g[3], q1 = g[4], q2 = g[5], q3 = g[6];

    // Prefetch ring: record u -> dq components at floats {3,4,5,6}.
    float  w[UPF];   // float 3
    float4 v[UPF];   // floats 4..7 (use .x,.y,.z)
#pragma unroll
    for (int u = 0; u < UPF; ++u) {
        const float* p = rec + (size_t)u * REC;
        w[u] = p[3];
        v[u] = *reinterpret_cast<const float4*>(p + 4);
    }

    if (TO_WS) {
        float4 o = make_float4(q0, q1, q2, q3);
        *reinterpret_cast<float4*>(dst + (size_t)r * SEQ * 4) = o;
    } else {
        float* o = dst + (size_t)r * SEQ * SD;
        o[3] = q0; o[4] = q1; o[5] = q2; o[6] = q3;
    }

    // 7 full groups of 16 steps (t = 1..112), refilling the ring one group
    // ahead; then a 15-step tail (t = 113..127) consuming the last records.
    for (int t0 = 0; t0 + UPF < SEQ; t0 += UPF) {
#pragma unroll
        for (int u = 0; u < UPF; ++u) {
            const int t = t0 + u + 1;
            q0 += w[u] * 0.1f;
            q1 += v[u].x * 0.1f;
            q2 += v[u].y * 0.1f;
            q3 += v[u].z * 0.1f;
            // refill slot u with record (t0 + UPF + u)  [max index 127, valid]
            const float* p = rec + (size_t)(t0 + UPF + u) * REC;
            w[u] = p[3];
            v[u] = *reinterpret_cast<const float4*>(p + 4);
            const float n   = q0 * q0 + q1 * q1 + q2 * q2 + q3 * q3;
            const float inv = __builtin_amdgcn_rsqf(n);
            q0 *= inv; q1 *= inv; q2 *= inv; q3 *= inv;
            if (TO_WS) {
                float4 o = make_float4(q0, q1, q2, q3);
                *reinterpret_cast<float4*>(dst + ((size_t)r * SEQ + t) * 4) = o;
            } else {
                float* o = dst + ((size_t)r * SEQ + t) * SD;
                o[3] = q0; o[4] = q1; o[5] = q2; o[6] = q3;
            }
        }
    }
#pragma unroll
    for (int u = 0; u < UPF - 1; ++u) {
        const int t = (SEQ - UPF) + u + 1;   // 113..127
        q0 += w[u] * 0.1f;
        q1 += v[u].x * 0.1f;
        q2 += v[u].y * 0.1f;
        q3 += v[u].z * 0.1f;
        const float n   = q0 * q0 + q1 * q1 + q2 * q2 + q3 * q3;
        const float inv = __builtin_amdgcn_rsqf(n);
        q0 *= inv; q1 *= inv; q2 *= inv; q3 *= inv;
        if (TO_WS) {
            float4 o = make_float4(q0, q1, q2, q3);
            *reinterpret_cast<float4*>(dst + ((size_t)r * SEQ + t) * 4) = o;
        } else {
            float* o = dst + ((size_t)r * SEQ + t) * SD;
            o[3] = q0; o[4] = q1; o[5] = q2; o[6] = q3;
        }
    }
}

// ---------------------------------------------------------------------------
// K2: one row per block.  Shuffle-scan positions, merge quats from ws,
// assemble packed 15-float records in LDS (stride 15 is coprime with 32
// banks -> conflict-free), then write the whole 7680 B row as contiguous
// float4s: every 64 B line written exactly once, fully coalesced.
// ---------------------------------------------------------------------------
template <bool HAVE_WS>
__global__ __launch_bounds__(128) void assemble_kernel(const float* __restrict__ dba,
                                                       const float* __restrict__ gt,
                                                       const float4* __restrict__ wsq,
                                                       float* __restrict__ out) {
    const int b = blockIdx.x;
    const int s = threadIdx.x;
    const int lane = s & 63;
    const int wave = s >> 6;

    const float4 h = *reinterpret_cast<const float4*>(dba + ((size_t)b * SEQ + s) * REC);
    const float d0 = h.x * 0.1f, d1 = h.y * 0.1f, d2 = h.z * 0.1f;

    // Inclusive shuffle scan within each wave.
    float ix = d0, iy = d1, iz = d2;
#pragma unroll
    for (int off = 1; off < 64; off <<= 1) {
        const float tx = __shfl_up(ix, off, 64);
        const float ty = __shfl_up(iy, off, 64);
        const float tz = __shfl_up(iz, off, 64);
        if (lane >= off) { ix += tx; iy += ty; iz += tz; }
    }
    __shared__ float w0tot[3];
    if (wave == 0 && lane == 63) { w0tot[0] = ix; w0tot[1] = iy; w0tot[2] = iz; }
    __syncthreads();
    if (wave == 1) { ix += w0tot[0]; iy += w0tot[1]; iz += w0tot[2]; }

    const float ex = ix - d0, ey = iy - d1, ez = iz - d2;   // exclusive prefix

    const float* g = gt + (size_t)b * SEQ * SD;             // broadcast load
    const float px = g[0], py = g[1], pz = g[2];

    if (HAVE_WS) {
        const float4 q = wsq[(size_t)b * SEQ + s];          // coalesced 16 B/lane

        __shared__ float st[SEQ * SD];                      // packed 7680 B row
        float* rp = st + s * SD;
        rp[0] = px + ex; rp[1] = py + ey; rp[2] = pz + ez;
        rp[3] = q.x; rp[4] = q.y; rp[5] = q.z; rp[6] = q.w;
#pragma unroll
        for (int k = 7; k < SD; ++k) rp[k] = 0.f;
        __syncthreads();

        float4* o4 = reinterpret_cast<float4*>(out + (size_t)b * SEQ * SD);
        const float4* s4 = reinterpret_cast<const float4*>(st);
        for (int k = s; k < SEQ * SD / 4; k += 128)         // 480 float4s
            o4[k] = s4[k];
    } else {
        // Fallback: quat slots owned by quat_kernel<false>; write the rest.
        float* o = out + ((size_t)b * SEQ + s) * SD;
        o[0] = px + ex; o[1] = py + ey; o[2] = pz + ez;
#pragma unroll
        for (int k = 7; k < SD; ++k) o[k] = 0.f;
    }
}

extern "C" void kernel_launch(void* const* d_in, const int* in_sizes, int n_in,
                              void* d_out, int out_size, void* d_ws, size_t ws_size,
                              hipStream_t stream) {
    const float* dba = (const float*)d_in[0];   // (B, 128, 32)
    // d_in[1] = imu_measurements — unused by the reference
    const float* gt  = (const float*)d_in[2];   // (B, 128, 15)
    float* out = (float*)d_out;                 // (B, 128, 15)

    const int B = in_sizes[0] / (SEQ * REC);
    const int qblocks = (B + 63) / 64;
    const size_t wsNeed = (size_t)B * SEQ * 4 * sizeof(float);

    if (ws_size >= wsNeed) {
        float* wsq = (float*)d_ws;
        quat_kernel<true><<<qblocks, 64, 0, stream>>>(dba, gt, wsq, B);
        assemble_kernel<true><<<B, 128, 0, stream>>>(dba, gt, (const float4*)wsq, out);
    } else {
        quat_kernel<false><<<qblocks, 64, 0, stream>>>(dba, gt, out, B);
        assemble_kernel<false><<<B, 128, 0, stream>>>(dba, gt, nullptr, out);
    }
}